// Round 2
// baseline (3953.522 us; speedup 1.0000x reference)
//
#include <hip/hip_runtime.h>

// ---------------------------------------------------------------------------
// down_block11: FPS -> kNN(8) -> grouped feature MLPs -> offset attention.
// All fp32. B=8, C_IN=128, N=2048, K=8, S=512, C_MID=131.
//
// Workspace budget: 211.7 MB (region A = Gram -> f2 -> att serial reuse;
// m1+m2 fused so feats/f1 are never materialized).
// ---------------------------------------------------------------------------

#define NB 8
#define NN 2048
#define CIN 128
#define KNN 8
#define SS 512
#define CMID 131

enum { F_XT = 1, F_PERM = 2, F_STORET = 4, F_XSUB = 8 };

// Generic fp32 GEMM: Y[b][o][m] = epilogue( sum_k W[o][k] * X[b][k][m] )
// Epilogue: (+bias[o]) -> (*gamma[o]+beta[o]) -> relu -> (+skip) -> (*colscale)
template <int BO, int BM, int FLAGS>
__global__ __launch_bounds__(256) void gemm_k(
    const float* __restrict__ W, size_t wbs,
    const float* __restrict__ X, size_t xbs,
    const float* __restrict__ X2,
    float* __restrict__ Y, size_t ybs, int ldyt,
    int O, int K, int M,
    const float* __restrict__ bias,
    const float* __restrict__ gamma,
    const float* __restrict__ beta,
    const float* __restrict__ skip, size_t skipbs,
    const float* __restrict__ colscale,
    int relu)
{
    constexpr int KC = 16;
    constexpr int TO = BO / 16, TM = BM / 16;
    __shared__ float Wl[KC][BO + 4];
    __shared__ float Xl[KC][BM + 4];
    const int b  = blockIdx.z;
    const int o0 = blockIdx.y * BO, m0 = blockIdx.x * BM;
    const float* Wb  = W + (size_t)b * wbs;
    const float* Xb  = X + (size_t)b * xbs;
    const float* X2b = (FLAGS & F_XSUB) ? (X2 + (size_t)b * xbs) : nullptr;
    const int t  = threadIdx.x;
    const int to = t >> 4, tm = t & 15;

    float acc[TO][TM];
#pragma unroll
    for (int i = 0; i < TO; ++i)
#pragma unroll
        for (int j = 0; j < TM; ++j) acc[i][j] = 0.f;

    for (int kk = 0; kk < K; kk += KC) {
#pragma unroll
        for (int r = 0; r < BO * KC / 256; ++r) {
            int idx = t + r * 256;
            int o = idx >> 4, ki = idx & 15;
            int go = o0 + o, gk = kk + ki;
            float v = 0.f;
            if (go < O && gk < K) {
                if (FLAGS & F_PERM)
                    v = Wb[(size_t)go * K + ((gk & 7) << 8) + (gk >> 3)];
                else
                    v = Wb[(size_t)go * K + gk];
            }
            Wl[ki][o] = v;
        }
        if (FLAGS & F_XT) {
#pragma unroll
            for (int r = 0; r < BM * KC / 256; ++r) {
                int idx = t + r * 256;
                int m = idx >> 4, ki = idx & 15;
                int gm = m0 + m, gk = kk + ki;
                Xl[ki][m] = (gm < M && gk < K) ? Xb[(size_t)gm * K + gk] : 0.f;
            }
        } else {
#pragma unroll
            for (int r = 0; r < BM * KC / 256; ++r) {
                int idx = t + r * 256;
                int kr = idx / BM, mc = idx % BM;
                int gk = kk + kr, gm = m0 + mc;
                float v = 0.f;
                if (gk < K && gm < M) {
                    v = Xb[(size_t)gk * M + gm];
                    if (FLAGS & F_XSUB) v -= X2b[(size_t)gk * M + gm];
                }
                Xl[kr][mc] = v;
            }
        }
        __syncthreads();
#pragma unroll
        for (int k = 0; k < KC; ++k) {
            float wv[TO], xv[TM];
#pragma unroll
            for (int i = 0; i < TO; ++i) wv[i] = Wl[k][to * TO + i];
#pragma unroll
            for (int j = 0; j < TM; ++j) xv[j] = Xl[k][tm + 16 * j];
#pragma unroll
            for (int i = 0; i < TO; ++i)
#pragma unroll
                for (int j = 0; j < TM; ++j)
                    acc[i][j] = fmaf(wv[i], xv[j], acc[i][j]);
        }
        __syncthreads();
    }
#pragma unroll
    for (int i = 0; i < TO; ++i) {
        int o = o0 + to * TO + i;
        if (o >= O) continue;
        float bi_ = bias ? bias[o] : 0.f;
        float ga  = gamma ? gamma[o] : 1.f;
        float be  = gamma ? beta[o] : 0.f;
#pragma unroll
        for (int j = 0; j < TM; ++j) {
            int m = m0 + tm + 16 * j;
            if (m >= M) continue;
            float v = acc[i][j] + bi_;
            v = v * ga + be;
            if (relu) v = fmaxf(v, 0.f);
            if (skip) v += skip[(size_t)b * skipbs + (size_t)o * M + m];
            if (colscale) v *= colscale[(size_t)b * M + m];
            if (FLAGS & F_STORET)
                Y[(size_t)b * ybs + (size_t)m * ldyt + o] = v;
            else
                Y[(size_t)b * ybs + (size_t)o * M + m] = v;
        }
    }
}

// FPS: one block per batch; dist in registers; Gram rows give dots.
__global__ __launch_bounds__(256) void fps_k(const float* __restrict__ G,
                                             int* __restrict__ far)
{
    const int b = blockIdx.x;
    const float* Gb = G + (size_t)b * NN * NN;
    const int t = threadIdx.x;
    float dist[8], diag[8];
#pragma unroll
    for (int j = 0; j < 8; ++j) {
        int p = t + j * 256;
        diag[j] = Gb[(size_t)p * NN + p];
        dist[j] = 1e10f;
    }
    __shared__ float sv[4];
    __shared__ int   si[4];
    __shared__ int   sfar;
    int cur = 0;
    if (t == 0) far[b * SS] = 0;
    for (int it = 1; it < SS; ++it) {
        const float* row = Gb + (size_t)cur * NN;
        float nf = row[cur];
        float best = -1e30f;
        int bidx = 0;
#pragma unroll
        for (int j = 0; j < 8; ++j) {
            int p = t + j * 256;
            float d = diag[j] + nf - 2.0f * row[p];
            dist[j] = fminf(dist[j], d);
            if (dist[j] > best) { best = dist[j]; bidx = p; }
        }
#pragma unroll
        for (int off = 32; off >= 1; off >>= 1) {
            float ov = __shfl_xor(best, off, 64);
            int   oi = __shfl_xor(bidx, off, 64);
            if (ov > best || (ov == best && oi < bidx)) { best = ov; bidx = oi; }
        }
        int lane = t & 63, wid = t >> 6;
        if (lane == 0) { sv[wid] = best; si[wid] = bidx; }
        __syncthreads();
        if (t == 0) {
            float bb = sv[0]; int bi_ = si[0];
#pragma unroll
            for (int w = 1; w < 4; ++w)
                if (sv[w] > bb || (sv[w] == bb && si[w] < bi_)) { bb = sv[w]; bi_ = si[w]; }
            sfar = bi_;
            far[b * SS + it] = bi_;
        }
        __syncthreads();
        cur = sfar;
    }
}

// down[s][c] and downT[c][s] from feature rows selected by far
__global__ __launch_bounds__(256) void gather_df_k(const float* __restrict__ feature,
                                                   const int* __restrict__ far,
                                                   float* __restrict__ down,
                                                   float* __restrict__ downT)
{
    int idx = blockIdx.x * 256 + threadIdx.x;  // B*S*128
    int c = idx & 127;
    int s = (idx >> 7) & 511;
    int b = idx >> 16;
    float v = feature[(size_t)b * (NN * CIN) + (size_t)far[b * SS + s] * CIN + c];
    down[idx] = v;
    downT[((size_t)b * CIN + c) * SS + s] = v;
}

__global__ void gather_cx_k(const float* __restrict__ input,
                            const int* __restrict__ far,
                            float* __restrict__ cand,
                            float* __restrict__ candT)
{
    int idx = blockIdx.x * 64 + threadIdx.x;  // B*S
    if (idx >= NB * SS) return;
    int b = idx >> 9, s = idx & 511;
    int f = far[idx];
#pragma unroll
    for (int d = 0; d < 3; ++d) {
        float v = input[((size_t)b * 3 + d) * NN + f];
        cand[idx * 3 + d] = v;
        candT[((size_t)b * 3 + d) * SS + s] = v;
    }
}

// 8-NN among 512 candidates (3D), stable ties (smaller index first)
__global__ __launch_bounds__(256) void knn_k(const float* __restrict__ input,
                                             const float* __restrict__ cand,
                                             int* __restrict__ kidx)
{
    __shared__ float cx[SS], cy[SS], cz[SS], cn2[SS];
    int b = blockIdx.y;
    int t = threadIdx.x;
#pragma unroll
    for (int r = 0; r < 2; ++r) {
        int s = t + r * 256;
        float x = cand[(b * SS + s) * 3 + 0];
        float y = cand[(b * SS + s) * 3 + 1];
        float z = cand[(b * SS + s) * 3 + 2];
        cx[s] = x; cy[s] = y; cz[s] = z;
        cn2[s] = x * x + y * y + z * z;
    }
    __syncthreads();
    int n = blockIdx.x * 256 + t;
    float px = input[(size_t)b * (3 * NN) + n];
    float py = input[(size_t)b * (3 * NN) + NN + n];
    float pz = input[(size_t)b * (3 * NN) + 2 * NN + n];
    float pn2 = px * px + py * py + pz * pz;
    float bd[8]; int bi[8];
#pragma unroll
    for (int i = 0; i < 8; ++i) { bd[i] = 1e30f; bi[i] = 0; }
    for (int s = 0; s < SS; ++s) {
        float d = pn2 + cn2[s] - 2.f * (px * cx[s] + py * cy[s] + pz * cz[s]);
        if (d < bd[7]) {
            float v = d; int vi = s;
#pragma unroll
            for (int p = 0; p < 8; ++p) {
                bool sw = v < bd[p];
                float tv = sw ? bd[p] : v;
                int   ti = sw ? bi[p] : vi;
                if (sw) { bd[p] = v; bi[p] = vi; }
                v = tv; vi = ti;
            }
        }
    }
#pragma unroll
    for (int k = 0; k < 8; ++k)
        kidx[((size_t)b * NN + n) * 8 + k] = bi[k];
}

// skip pre-max: sk[b][c][n] = max_k feats[b][c][k][n], recomputed from gathers
__global__ __launch_bounds__(256) void skipfeat_k(const float* __restrict__ downT,
                                                  const float* __restrict__ candT,
                                                  const float* __restrict__ input,
                                                  const int* __restrict__ kidx,
                                                  float* __restrict__ sk)
{
    int b = blockIdx.z, c = blockIdx.y;
    int n = blockIdx.x * 256 + threadIdx.x;
    const int* kp = &kidx[((size_t)b * NN + n) * 8];
    int id[8];
#pragma unroll
    for (int k = 0; k < 8; ++k) id[k] = kp[k];
    float m;
    if (c < CIN) {
        const float* dc = &downT[((size_t)b * CIN + c) * SS];
        m = dc[id[0]];
#pragma unroll
        for (int k = 1; k < 8; ++k) m = fmaxf(m, dc[id[k]]);
    } else {
        int d = c - CIN;
        const float* cc = &candT[((size_t)b * 3 + d) * SS];
        float x = input[(size_t)b * (3 * NN) + (size_t)d * NN + n];
        m = cc[id[0]] - x;
#pragma unroll
        for (int k = 1; k < 8; ++k) m = fmaxf(m, cc[id[k]] - x);
    }
    sk[((size_t)b * CMID + c) * NN + n] = m;
}

// Fused m1+m2: gathers feats tile -> LDS, f1 = relu(W1.feats) in LDS,
// f2 = relu(bn(W2.f1)) -> global rows rr = w*8+k (layout for out1 GEMM).
// Block = (ntile of 32 n's, neighbor k, batch). LDS 69.5 KB -> 2 blocks/CU.
__global__ __launch_bounds__(256) void mlp12_k(const float* __restrict__ down,
                                               const float* __restrict__ cand,
                                               const float* __restrict__ input,
                                               const int* __restrict__ kidx,
                                               const float* __restrict__ W1,
                                               const float* __restrict__ W2,
                                               const float* __restrict__ g2,
                                               const float* __restrict__ b2,
                                               float* __restrict__ f2)
{
    __shared__ float featsL[144][33];  // rows 131..143 zero
    __shared__ float f1L[256][33];
    __shared__ float WL[16][260];
    __shared__ int   kl[32];
    const int b = blockIdx.z, k = blockIdx.y;
    const int n0 = blockIdx.x * 32;
    const int t = threadIdx.x;
    if (t < 32) kl[t] = kidx[((size_t)b * NN + n0 + t) * 8 + k];
    __syncthreads();
    for (int e = t; e < 32 * 160; e += 256) {   // n-major: coalesced down rows
        int n = e / 160, c = e % 160;
        if (c >= 144) continue;
        float v = 0.f;
        if (c < CIN) v = down[((size_t)b * SS + kl[n]) * CIN + c];
        else if (c < CMID) {
            int d = c - CIN;
            v = cand[((size_t)b * SS + kl[n]) * 3 + d]
              - input[(size_t)b * (3 * NN) + (size_t)d * NN + n0 + n];
        }
        featsL[c][n] = v;
    }
    __syncthreads();
    const int to = t >> 4, tm = t & 15;
    const int obase = to * 16;
    float acc0[16], acc1[16];
#pragma unroll
    for (int i = 0; i < 16; ++i) { acc0[i] = 0.f; acc1[i] = 0.f; }
    // stage A: f1 = relu(W1 . feats), K padded to 144
    for (int kk = 0; kk < 144; kk += 16) {
#pragma unroll
        for (int r = 0; r < 16; ++r) {
            int e = t + r * 256;
            int o = e >> 4, ki = e & 15;
            int gk = kk + ki;
            WL[ki][o] = (gk < CMID) ? W1[o * CMID + gk] : 0.f;
        }
        __syncthreads();
#pragma unroll
        for (int ki = 0; ki < 16; ++ki) {
            float x0 = featsL[kk + ki][tm], x1 = featsL[kk + ki][tm + 16];
            const float* wrow = &WL[ki][obase];
#pragma unroll
            for (int i = 0; i < 16; ++i) {
                float w = wrow[i];
                acc0[i] = fmaf(w, x0, acc0[i]);
                acc1[i] = fmaf(w, x1, acc1[i]);
            }
        }
        __syncthreads();
    }
#pragma unroll
    for (int i = 0; i < 16; ++i) {
        f1L[obase + i][tm]      = fmaxf(acc0[i], 0.f);
        f1L[obase + i][tm + 16] = fmaxf(acc1[i], 0.f);
    }
    __syncthreads();
#pragma unroll
    for (int i = 0; i < 16; ++i) { acc0[i] = 0.f; acc1[i] = 0.f; }
    // stage B: f2 = relu(bn(W2 . f1))
    for (int kk = 0; kk < 256; kk += 16) {
#pragma unroll
        for (int r = 0; r < 16; ++r) {
            int e = t + r * 256;
            int o = e >> 4, ki = e & 15;
            WL[ki][o] = W2[o * 256 + kk + ki];
        }
        __syncthreads();
#pragma unroll
        for (int ki = 0; ki < 16; ++ki) {
            float x0 = f1L[kk + ki][tm], x1 = f1L[kk + ki][tm + 16];
            const float* wrow = &WL[ki][obase];
#pragma unroll
            for (int i = 0; i < 16; ++i) {
                float w = wrow[i];
                acc0[i] = fmaf(w, x0, acc0[i]);
                acc1[i] = fmaf(w, x1, acc1[i]);
            }
        }
        __syncthreads();
    }
#pragma unroll
    for (int i = 0; i < 16; ++i) {
        int o = obase + i;
        float ga = g2[o], be = b2[o];
        size_t base = (size_t)b * ((size_t)NN * NN) + (size_t)(o * 8 + k) * NN + n0;
        f2[base + tm]      = fmaxf(fmaf(acc0[i], ga, be), 0.f);
        f2[base + tm + 16] = fmaxf(fmaf(acc1[i], ga, be), 0.f);
    }
}

__global__ void globin_k(const float* __restrict__ input, float* __restrict__ glob)
{
    int idx = blockIdx.x * 256 + threadIdx.x;  // B*3*N
    int b = idx / (3 * NN), rem = idx % (3 * NN);
    glob[(size_t)b * (CMID * NN) + (size_t)(CIN * NN) + rem] = input[idx];
}

__global__ __launch_bounds__(256) void softmax_k(float* __restrict__ att)
{
    int b = blockIdx.y;
    float* row = att + ((size_t)b * NN + blockIdx.x) * NN;
    int t = threadIdx.x;
    float x[8];
#pragma unroll
    for (int r = 0; r < 8; ++r) x[r] = row[t + r * 256];
    float m = x[0];
#pragma unroll
    for (int r = 1; r < 8; ++r) m = fmaxf(m, x[r]);
#pragma unroll
    for (int off = 32; off >= 1; off >>= 1) m = fmaxf(m, __shfl_xor(m, off, 64));
    __shared__ float sh[4];
    int wid = t >> 6, lane = t & 63;
    if (lane == 0) sh[wid] = m;
    __syncthreads();
    m = fmaxf(fmaxf(sh[0], sh[1]), fmaxf(sh[2], sh[3]));
    float s = 0.f;
#pragma unroll
    for (int r = 0; r < 8; ++r) { x[r] = expf(x[r] - m); s += x[r]; }
#pragma unroll
    for (int off = 32; off >= 1; off >>= 1) s += __shfl_xor(s, off, 64);
    __syncthreads();
    if (lane == 0) sh[wid] = s;
    __syncthreads();
    s = sh[0] + sh[1] + sh[2] + sh[3];
#pragma unroll
    for (int r = 0; r < 8; ++r) row[t + r * 256] = x[r] / s;
}

__global__ __launch_bounds__(256) void colsum_part_k(const float* __restrict__ att,
                                                     float* __restrict__ part)
{
    int j = blockIdx.x * 256 + threadIdx.x;
    int rc = blockIdx.y, b = blockIdx.z;
    const float* p = att + (size_t)b * NN * NN + (size_t)rc * 256 * NN + j;
    float s = 0.f;
    for (int i = 0; i < 256; ++i) s += p[(size_t)i * NN];
    part[((size_t)b * 8 + rc) * NN + j] = s;
}

__global__ __launch_bounds__(256) void colsum_fin_k(const float* __restrict__ part,
                                                    float* __restrict__ inv)
{
    int j = blockIdx.x * 256 + threadIdx.x;
    int b = blockIdx.y;
    float s = 0.f;
#pragma unroll
    for (int r = 0; r < 8; ++r) s += part[((size_t)b * 8 + r) * NN + j];
    inv[b * NN + j] = 1.f / (1e-9f + s);
}

// ---------------------------------------------------------------------------
extern "C" void kernel_launch(void* const* d_in, const int* in_sizes, int n_in,
                              void* d_out, int out_size, void* d_ws, size_t ws_size,
                              hipStream_t stream)
{
    (void)in_sizes; (void)n_in; (void)out_size;
    const float* feature = (const float*)d_in[0];
    const float* input   = (const float*)d_in[1];
    const float* w_skip  = (const float*)d_in[3];
    const float* g_skip  = (const float*)d_in[4];
    const float* b_skip  = (const float*)d_in[5];
    const float* w_m1    = (const float*)d_in[6];
    const float* w_m2    = (const float*)d_in[7];
    const float* g_m2    = (const float*)d_in[8];
    const float* b_m2    = (const float*)d_in[9];
    const float* w_out1  = (const float*)d_in[10];
    const float* g_out1  = (const float*)d_in[11];
    const float* b_out1  = (const float*)d_in[12];
    const float* w_out2  = (const float*)d_in[13];
    const float* g_out2  = (const float*)d_in[14];
    const float* b_out2  = (const float*)d_in[15];
    const float* w_q     = (const float*)d_in[16];
    const float* w_k     = (const float*)d_in[17];
    const float* w_v     = (const float*)d_in[18];
    const float* b_v     = (const float*)d_in[19];
    const float* w_t     = (const float*)d_in[20];
    const float* b_t     = (const float*)d_in[21];
    const float* g_ra    = (const float*)d_in[22];
    const float* b_ra    = (const float*)d_in[23];
    const float* w_mlp1  = (const float*)d_in[24];
    const float* w_conv2 = (const float*)d_in[25];
    const float* g_conv2 = (const float*)d_in[26];
    const float* b_conv2 = (const float*)d_in[27];
    float* out = (float*)d_out;
    float* ws  = (float*)d_ws;

    // Required workspace: 52,932,608 floats = 211.7 MB.
    // Diagnostic guard: if scratch is smaller, do nothing (fails with wrong
    // answer rather than a memory-fault abort).
    if (ws_size < (size_t)52932608 * 4) return;

    // region A (32M floats): Gram -> f2 -> att (strictly serial lifetimes)
    float* A     = ws;
    float* G     = A;
    float* f2    = A;
    float* att   = A;
    int*   far   = (int*)(ws + 33554432);
    float* down  = ws + 33558528;
    float* downT = ws + 34082816;
    float* cand  = ws + 34607104;
    float* candT = ws + 34619392;
    int*   kidx  = (int*)(ws + 34631680);
    float* skmax = ws + 34762752;
    float* skip2 = ws + 36909056;   // later reused as `mid`
    float* g1    = ws + 41103360;   // later reused as `x_r`
    float* glob  = ws + 45297664;
    float* q_t   = ws + 47443968;
    float* kkb   = ws + 47968256;
    float* vb    = ws + 48492544;
    float* ics   = ws + 50638848;
    float* csp   = ws + 50655232;
    float* ra    = ws + 50786304;
    float* mid   = skip2;
    float* x_r   = g1;

    const size_t GLB = (size_t)CMID * NN;  // 268288

    // 1. Gram G = pts . pts^T  (pts = feature viewed (N x 128) per batch)
    gemm_k<128, 128, F_XT><<<dim3(16, 16, NB), 256, 0, stream>>>(
        feature, (size_t)NN * CIN, feature, (size_t)NN * CIN, nullptr,
        G, (size_t)NN * NN, 0, NN, CIN, NN,
        nullptr, nullptr, nullptr, nullptr, 0, nullptr, 0);
    // 2. FPS
    fps_k<<<NB, 256, 0, stream>>>(G, far);
    // 3. gathers
    gather_df_k<<<(NB * SS * CIN) / 256, 256, 0, stream>>>(feature, far, down, downT);
    gather_cx_k<<<(NB * SS) / 64, 64, 0, stream>>>(input, far, cand, candT);
    // 4. kNN
    knn_k<<<dim3(NN / 256, NB), 256, 0, stream>>>(input, cand, kidx);
    // 5. skip pre-max + skip conv
    skipfeat_k<<<dim3(NN / 256, CMID, NB), 256, 0, stream>>>(downT, candT, input, kidx, skmax);
    gemm_k<128, 128, 0><<<dim3(16, 2, NB), 256, 0, stream>>>(
        w_skip, 0, skmax, GLB, nullptr, skip2, (size_t)256 * NN, 0,
        256, CMID, NN, nullptr, g_skip, b_skip, nullptr, 0, nullptr, 1);
    // 6. fused m1+m2 -> f2 (overwrites Gram; FPS already done)
    mlp12_k<<<dim3(NN / 32, KNN, NB), 256, 0, stream>>>(
        down, cand, input, kidx, w_m1, w_m2, g_m2, b_m2, f2);
    // 7. out1: g1 = relu(bn(Wperm . f2)) + skip2
    gemm_k<128, 128, F_PERM><<<dim3(16, 2, NB), 256, 0, stream>>>(
        w_out1, 0, f2, (size_t)NN * NN, nullptr, g1, (size_t)256 * NN, 0,
        256, 2048, NN, nullptr, g_out1, b_out1, skip2, (size_t)256 * NN, nullptr, 1);
    // 8. out2 -> glob rows 0..127 ; rows 128..130 = input
    gemm_k<128, 128, 0><<<dim3(16, 1, NB), 256, 0, stream>>>(
        w_out2, 0, g1, (size_t)256 * NN, nullptr, glob, GLB, 0,
        128, 256, NN, nullptr, g_out2, b_out2, nullptr, 0, nullptr, 1);
    globin_k<<<(NB * 3 * NN) / 256, 256, 0, stream>>>(input, glob);
    // 9. q (stored transposed), k, v
    gemm_k<64, 64, F_STORET><<<dim3(32, 1, NB), 256, 0, stream>>>(
        w_q, 0, glob, GLB, nullptr, q_t, (size_t)NN * 32, 32,
        32, CMID, NN, nullptr, nullptr, nullptr, nullptr, 0, nullptr, 0);
    gemm_k<64, 64, 0><<<dim3(32, 1, NB), 256, 0, stream>>>(
        w_k, 0, glob, GLB, nullptr, kkb, (size_t)32 * NN, 0,
        32, CMID, NN, nullptr, nullptr, nullptr, nullptr, 0, nullptr, 0);
    gemm_k<64, 64, 0><<<dim3(32, 3, NB), 256, 0, stream>>>(
        w_v, 0, glob, GLB, nullptr, vb, GLB, 0,
        CMID, CMID, NN, b_v, nullptr, nullptr, nullptr, 0, nullptr, 0);
    // 10. att = q^T . k (overwrites f2 region; out1 already done)
    gemm_k<128, 128, 0><<<dim3(16, 16, NB), 256, 0, stream>>>(
        q_t, (size_t)NN * 32, kkb, (size_t)32 * NN, nullptr, att, (size_t)NN * NN, 0,
        NN, 32, NN, nullptr, nullptr, nullptr, nullptr, 0, nullptr, 0);
    softmax_k<<<dim3(NN, NB), 256, 0, stream>>>(att);
    colsum_part_k<<<dim3(NN / 256, 8, NB), 256, 0, stream>>>(att, csp);
    colsum_fin_k<<<dim3(NN / 256, NB), 256, 0, stream>>>(csp, ics);
    // 11. x_r = (v . att) * ics
    gemm_k<128, 128, 0><<<dim3(16, 2, NB), 256, 0, stream>>>(
        vb, GLB, att, (size_t)NN * NN, nullptr, x_r, GLB, 0,
        CMID, NN, NN, nullptr, nullptr, nullptr, nullptr, 0, ics, 0);
    // 12. ra = glob + relu(bn(w_t . (glob - x_r) + b_t))
    gemm_k<64, 64, F_XSUB><<<dim3(32, 3, NB), 256, 0, stream>>>(
        w_t, 0, glob, GLB, x_r, ra, GLB, 0,
        CMID, CMID, NN, b_t, g_ra, b_ra, glob, GLB, nullptr, 1);
    // 13. out = relu(bn(w_conv2 . relu(w_mlp1 . ra)))
    gemm_k<128, 128, 0><<<dim3(16, 2, NB), 256, 0, stream>>>(
        w_mlp1, 0, ra, GLB, nullptr, mid, (size_t)256 * NN, 0,
        256, CMID, NN, nullptr, nullptr, nullptr, nullptr, 0, nullptr, 1);
    gemm_k<128, 128, 0><<<dim3(16, 1, NB), 256, 0, stream>>>(
        w_conv2, 0, mid, (size_t)256 * NN, nullptr, out, (size_t)128 * NN, 0,
        128, 256, NN, nullptr, g_conv2, b_conv2, nullptr, 0, nullptr, 1);
}